// Round 1
// baseline (594.239 us; speedup 1.0000x reference)
//
#include <hip/hip_runtime.h>

// Problem constants (fixed by reference): N=B*T=65536, D=256, K=1024
#define NTOT 65536
#define DDIM 256
#define KCB  1024
#define ND   16777216   // NTOT * DDIM
#define AS_STRIDE 68    // 68 floats = 272 B = 17*16 B -> every row 16B-aligned, breaks pow2 bank stride

// Kernel A: half_esq[k] = 0.5 * sum_d cb[k][d]^2 ; also zero the loss accumulator.
// grid = 16 blocks x 256 threads; each wave handles 16 codebook rows.
__global__ __launch_bounds__(256) void vq_esq_kernel(const float* __restrict__ cb,
                                                     float* __restrict__ half_esq,
                                                     float* __restrict__ loss_out) {
    int tid  = threadIdx.x;
    int wave = tid >> 6;
    int lane = tid & 63;
    int kbase = (blockIdx.x * 4 + wave) * 16;
    for (int kk = 0; kk < 16; ++kk) {
        int k = kbase + kk;
        const float* row = cb + k * DDIM;
        float s = 0.f;
        #pragma unroll
        for (int j = 0; j < 4; ++j) {
            float v = row[lane + j * 64];
            s += v * v;
        }
        #pragma unroll
        for (int off = 32; off; off >>= 1) s += __shfl_down(s, off);
        if (lane == 0) half_esq[k] = 0.5f * s;
    }
    if (blockIdx.x == 0 && tid == 0) loss_out[0] = 0.f;
}

// Kernel B: fused distance-GEMM + argmin + gather + commitment loss.
// grid = N/64 = 1024 blocks x 256 threads. Each block: 64 rows x all K.
__global__ __launch_bounds__(256) void vq_main_kernel(const float* __restrict__ z,
                                                      const float* __restrict__ cb,
                                                      const float* __restrict__ half_esq,
                                                      float* __restrict__ out) {
    __shared__ float As[32 * AS_STRIDE];   // A chunk, transposed: As[d][row]
    __shared__ float Bs[32 * AS_STRIDE];   // B chunk, transposed: Bs[d][col]
    __shared__ float esq_s[KCB];
    __shared__ float bestv_s[64 * 16];
    __shared__ int   bestk_s[64 * 16];
    __shared__ int   idx_s[64];
    __shared__ float wsum_s[4];

    const int tid = threadIdx.x;
    const int tx = tid & 15;       // col group (4 cols each)
    const int ty = tid >> 4;       // row group (4 rows each)
    const int r0 = blockIdx.x * 64;

    for (int k = tid; k < KCB; k += 256) esq_s[k] = half_esq[k];

    float bestv[4] = {-1e30f, -1e30f, -1e30f, -1e30f};
    int   bestk[4] = {0, 0, 0, 0};

    for (int kt = 0; kt < 16; ++kt) {
        float acc[4][4] = {{0.f}};
        for (int c = 0; c < 8; ++c) {
            const int d0 = c * 32;
            __syncthreads();
            // Stage A (64 rows x 32 d) and B (64 cols x 32 d), transposed into LDS.
            #pragma unroll
            for (int u = 0; u < 2; ++u) {
                const int lid = tid + u * 256;        // 0..511
                const int row = lid >> 3;             // 0..63
                const int d4  = (lid & 7) * 4;        // 0..28
                float4 av = *(const float4*)&z[(size_t)(r0 + row) * DDIM + d0 + d4];
                As[(d4 + 0) * AS_STRIDE + row] = av.x;
                As[(d4 + 1) * AS_STRIDE + row] = av.y;
                As[(d4 + 2) * AS_STRIDE + row] = av.z;
                As[(d4 + 3) * AS_STRIDE + row] = av.w;
                float4 bv = *(const float4*)&cb[(size_t)(kt * 64 + row) * DDIM + d0 + d4];
                Bs[(d4 + 0) * AS_STRIDE + row] = bv.x;
                Bs[(d4 + 1) * AS_STRIDE + row] = bv.y;
                Bs[(d4 + 2) * AS_STRIDE + row] = bv.z;
                Bs[(d4 + 3) * AS_STRIDE + row] = bv.w;
            }
            __syncthreads();
            #pragma unroll
            for (int d = 0; d < 32; ++d) {
                float4 a = *(const float4*)&As[d * AS_STRIDE + ty * 4];
                float4 b = *(const float4*)&Bs[d * AS_STRIDE + tx * 4];
                acc[0][0] += a.x * b.x; acc[0][1] += a.x * b.y; acc[0][2] += a.x * b.z; acc[0][3] += a.x * b.w;
                acc[1][0] += a.y * b.x; acc[1][1] += a.y * b.y; acc[1][2] += a.y * b.z; acc[1][3] += a.y * b.w;
                acc[2][0] += a.z * b.x; acc[2][1] += a.z * b.y; acc[2][2] += a.z * b.z; acc[2][3] += a.z * b.w;
                acc[3][0] += a.w * b.x; acc[3][1] += a.w * b.y; acc[3][2] += a.w * b.z; acc[3][3] += a.w * b.w;
            }
        }
        // score = cross - 0.5*||e||^2 ; argmin(dist) == argmax(score).
        // k ascends per thread across (kt, j) -> strict '>' keeps first (lowest) index on ties.
        #pragma unroll
        for (int i = 0; i < 4; ++i) {
            #pragma unroll
            for (int j = 0; j < 4; ++j) {
                const int k = kt * 64 + tx * 4 + j;
                const float s = acc[i][j] - esq_s[k];
                if (s > bestv[i]) { bestv[i] = s; bestk[i] = k; }
            }
        }
    }

    #pragma unroll
    for (int i = 0; i < 4; ++i) {
        bestv_s[(ty * 4 + i) * 16 + tx] = bestv[i];
        bestk_s[(ty * 4 + i) * 16 + tx] = bestk[i];
    }
    __syncthreads();
    if (tid < 64) {
        float bv = bestv_s[tid * 16];
        int   bk = bestk_s[tid * 16];
        for (int t = 1; t < 16; ++t) {
            float v = bestv_s[tid * 16 + t];
            int  kk = bestk_s[tid * 16 + t];
            if (v > bv || (v == bv && kk < bk)) { bv = v; bk = kk; }
        }
        idx_s[tid] = bk;
    }
    __syncthreads();

    // Epilogue: gather z_q = cb[idx], write out, accumulate commitment loss.
    float lsum = 0.f;
    for (int it = 0; it < 64; ++it) {
        const int k = idx_s[it];
        const float q  = cb[(size_t)k * DDIM + tid];
        const float zz = z[(size_t)(r0 + it) * DDIM + tid];
        out[(size_t)(r0 + it) * DDIM + tid] = q;
        const float df = q - zz;
        lsum += df * df;
    }
    #pragma unroll
    for (int off = 32; off; off >>= 1) lsum += __shfl_down(lsum, off);
    const int lane = tid & 63, wid = tid >> 6;
    if (lane == 0) wsum_s[wid] = lsum;
    __syncthreads();
    if (tid == 0) {
        const float s = wsum_s[0] + wsum_s[1] + wsum_s[2] + wsum_s[3];
        atomicAdd(out + ND, s * (1.0f / (float)ND));
    }
}

extern "C" void kernel_launch(void* const* d_in, const int* in_sizes, int n_in,
                              void* d_out, int out_size, void* d_ws, size_t ws_size,
                              hipStream_t stream) {
    const float* z  = (const float*)d_in[0];   // z_e, 65536 x 256 fp32
    const float* cb = (const float*)d_in[1];   // codebook, 1024 x 256 fp32
    float* out = (float*)d_out;                // z_q (16777216) ++ loss (1)
    float* half_esq = (float*)d_ws;            // 1024 floats of scratch

    vq_esq_kernel<<<16, 256, 0, stream>>>(cb, half_esq, out + ND);
    vq_main_kernel<<<NTOT / 64, 256, 0, stream>>>(z, cb, half_esq, out);
}

// Round 2
// 173.440 us; speedup vs baseline: 3.4262x; 3.4262x over previous
//
#include <hip/hip_runtime.h>
#include <hip/hip_bf16.h>

// Problem constants: N=B*T=65536, D=256, K=1024
#define NTOT 65536
#define DDIM 256
#define KCB  1024
#define ND   16777216   // NTOT * DDIM

typedef __attribute__((ext_vector_type(8))) short bf16x8;   // 8 bf16 = 4 VGPRs
typedef __attribute__((ext_vector_type(4))) float f32x4;

__device__ static inline short f2bf(float f) {
    union { __hip_bfloat16 h; short s; } u;
    u.h = __float2bfloat16(f);   // RNE
    return u.s;
}

// ---------------- Kernel A: half_esq[k] = 0.5*||cb_k||^2 (fp32), zero loss ----
__global__ __launch_bounds__(256) void vq_esq_kernel(const float* __restrict__ cb,
                                                     float* __restrict__ half_esq,
                                                     float* __restrict__ loss_out) {
    int tid  = threadIdx.x;
    int wave = tid >> 6;
    int lane = tid & 63;
    int kbase = (blockIdx.x * 4 + wave) * 16;
    for (int kk = 0; kk < 16; ++kk) {
        int k = kbase + kk;
        const float* row = cb + k * DDIM;
        float s = 0.f;
        #pragma unroll
        for (int j = 0; j < 4; ++j) {
            float v = row[lane + j * 64];
            s += v * v;
        }
        #pragma unroll
        for (int off = 32; off; off >>= 1) s += __shfl_down(s, off);
        if (lane == 0) half_esq[k] = 0.5f * s;
    }
    if (blockIdx.x == 0 && tid == 0) loss_out[0] = 0.f;
}

// ---------------- Kernel B: codebook fp32 -> bf16, MFMA-B-fragment-linear -----
// Linear slot s (8 bf16 = 16 B each), s = ((((r*2+cg)*4+cf)*8+ks)*64 + l):
//   code = r*128 + cg*64 + cf*16 + (l&15),  d = ks*32 + (l>>4)*8
// so the GEMM kernel's staging is a straight linear copy and every
// ds_read_b128 is at (uniform + lane*16) -> conflict-free.
__global__ __launch_bounds__(256) void vq_convert_kernel(const float* __restrict__ cb,
                                                         short* __restrict__ cbf) {
    int s  = blockIdx.x * 256 + threadIdx.x;   // 0..32767
    int l  = s & 63;
    int ks = (s >> 6) & 7;
    int cf = (s >> 9) & 3;
    int cg = (s >> 11) & 1;
    int r  = s >> 12;
    int code = r * 128 + cg * 64 + cf * 16 + (l & 15);
    int d    = ks * 32 + (l >> 4) * 8;
    const float* p = cb + (size_t)code * DDIM + d;
    f32x4 x = *(const f32x4*)p;
    f32x4 y = *(const f32x4*)(p + 4);
    bf16x8 o;
    o[0] = f2bf(x[0]); o[1] = f2bf(x[1]); o[2] = f2bf(x[2]); o[3] = f2bf(x[3]);
    o[4] = f2bf(y[0]); o[5] = f2bf(y[1]); o[6] = f2bf(y[2]); o[7] = f2bf(y[3]);
    *(bf16x8*)(cbf + (size_t)s * 8) = o;
}

// ---------------- Kernel C: fused bf16-MFMA GEMM + argmin + gather + loss -----
// 1024 blocks x 256 thr (4 waves as 2 row-groups x 2 col-groups).
// Block: 64 rows x all 1024 codes. A-frags in regs (fp32->bf16 inline).
// 8 rounds of 128 staged codes (64 KB LDS via global_load_lds width-16).
__global__ __launch_bounds__(256, 2) void vq_gemm_kernel(const float* __restrict__ z,
                                                         const float* __restrict__ cb,
                                                         const short* __restrict__ cbf,
                                                         const float* __restrict__ half_esq,
                                                         float* __restrict__ out) {
    __shared__ short Bs[32768];     // 64 KB staged B fragments
    __shared__ float esq_s[KCB];    // 4 KB

    const int tid  = threadIdx.x;
    const int w    = tid >> 6;
    const int lane = tid & 63;
    const int rg   = w >> 1;        // row-group (32 rows)
    const int cg   = w & 1;         // col-group (64 of the 128 staged cols)
    const int q    = lane >> 4;
    const int ln   = lane & 15;
    const int b0   = blockIdx.x * 64;
    const int R0   = b0 + rg * 32;

    #pragma unroll
    for (int i = 0; i < 4; ++i) esq_s[tid + i * 256] = half_esq[tid + i * 256];

    // A fragments: a[rf][ks] covers rows R0+rf*16..+15, k = ks*32..+31.
    // Lane layout: A[m=lane&15][k = (lane>>4)*8 + j].
    bf16x8 a[2][8];
    #pragma unroll
    for (int rf = 0; rf < 2; ++rf) {
        const float* ap0 = z + (size_t)(R0 + rf * 16 + ln) * DDIM + q * 8;
        #pragma unroll
        for (int ks = 0; ks < 8; ++ks) {
            const float* ap = ap0 + ks * 32;
            f32x4 x = *(const f32x4*)ap;
            f32x4 y = *(const f32x4*)(ap + 4);
            bf16x8 t;
            t[0] = f2bf(x[0]); t[1] = f2bf(x[1]); t[2] = f2bf(x[2]); t[3] = f2bf(x[3]);
            t[4] = f2bf(y[0]); t[5] = f2bf(y[1]); t[6] = f2bf(y[2]); t[7] = f2bf(y[3]);
            a[rf][ks] = t;
        }
    }

    float bestv[8];
    int   bestk[8];
    #pragma unroll
    for (int i = 0; i < 8; ++i) { bestv[i] = -1e30f; bestk[i] = 0; }

    const short* bbase = Bs + cg * 16384 + lane * 8;

    for (int r = 0; r < 8; ++r) {
        __syncthreads();   // previous round's LDS reads done
        {
            const char* gsrc = (const char*)cbf + (size_t)r * 65536 + w * 16384 + lane * 16;
            char*       ldst = (char*)Bs + w * 16384;   // wave-uniform; HW adds lane*16
            #pragma unroll
            for (int i = 0; i < 16; ++i)
                __builtin_amdgcn_global_load_lds(
                    (const __attribute__((address_space(1))) unsigned int*)(gsrc + i * 1024),
                    (__attribute__((address_space(3))) unsigned int*)(ldst + i * 1024),
                    16, 0, 0);
        }
        __syncthreads();   // staging visible

        f32x4 acc[2][4];
        #pragma unroll
        for (int rf = 0; rf < 2; ++rf)
            #pragma unroll
            for (int cf = 0; cf < 4; ++cf)
                acc[rf][cf] = (f32x4){0.f, 0.f, 0.f, 0.f};

        #pragma unroll
        for (int ks = 0; ks < 8; ++ks) {
            #pragma unroll
            for (int cf = 0; cf < 4; ++cf) {
                bf16x8 b = *(const bf16x8*)(bbase + cf * 4096 + ks * 512);
                acc[0][cf] = __builtin_amdgcn_mfma_f32_16x16x32_bf16(a[0][ks], b, acc[0][cf], 0, 0, 0);
                acc[1][cf] = __builtin_amdgcn_mfma_f32_16x16x32_bf16(a[1][ks], b, acc[1][cf], 0, 0, 0);
            }
        }

        // score = cross - 0.5||e||^2 ; C/D layout: col=lane&15, row=q*4+reg.
        // k ascends over (r, cf) per lane -> strict '>' keeps lowest index.
        #pragma unroll
        for (int cf = 0; cf < 4; ++cf) {
            int col = r * 128 + cg * 64 + cf * 16 + ln;
            float e = esq_s[col];
            #pragma unroll
            for (int rf = 0; rf < 2; ++rf)
                #pragma unroll
                for (int i = 0; i < 4; ++i) {
                    float s = acc[rf][cf][i] - e;
                    int slot = rf * 4 + i;
                    if (s > bestv[slot]) { bestv[slot] = s; bestk[slot] = col; }
                }
        }
    }

    // ---- cross-lane argmin reduce (reuse Bs for candidates) ----
    float* bv_s  = (float*)Bs;            // 64*16 floats (4 KB)
    int*   bk_s  = (int*)Bs + 1024;       // next 4 KB
    int*   idx_s = (int*)esq_s;           // esq no longer needed
    float* wsum_s = esq_s + 256;
    __syncthreads();                      // all waves done with Bs/esq
    #pragma unroll
    for (int rf = 0; rf < 2; ++rf)
        #pragma unroll
        for (int i = 0; i < 4; ++i) {
            int rr = rg * 32 + rf * 16 + q * 4 + i;   // block-local row
            bv_s[rr * 16 + ln] = bestv[rf * 4 + i];
            bk_s[rr * 16 + ln] = bestk[rf * 4 + i];
        }
    __syncthreads();
    if (tid < 64) {
        float bv = bv_s[tid * 16];
        int   bk = bk_s[tid * 16];
        for (int t = 1; t < 16; ++t) {
            float v = bv_s[tid * 16 + t];
            int  kk = bk_s[tid * 16 + t];
            if (v > bv || (v == bv && kk < bk)) { bv = v; bk = kk; }
        }
        idx_s[tid] = bk;
    }
    __syncthreads();

    // ---- epilogue: gather z_q (fp32 codebook), exact fp32 loss ----
    float lsum = 0.f;
    for (int it = 0; it < 64; ++it) {
        int k = idx_s[it];
        float qv = cb[(size_t)k * DDIM + tid];
        float zv = z[(size_t)(b0 + it) * DDIM + tid];
        out[(size_t)(b0 + it) * DDIM + tid] = qv;
        float df = qv - zv;
        lsum += df * df;
    }
    #pragma unroll
    for (int off = 32; off; off >>= 1) lsum += __shfl_down(lsum, off);
    if (lane == 0) wsum_s[w] = lsum;
    __syncthreads();
    if (tid == 0)
        atomicAdd(out + ND, (wsum_s[0] + wsum_s[1] + wsum_s[2] + wsum_s[3]) * (1.0f / (float)ND));
}

extern "C" void kernel_launch(void* const* d_in, const int* in_sizes, int n_in,
                              void* d_out, int out_size, void* d_ws, size_t ws_size,
                              hipStream_t stream) {
    const float* z  = (const float*)d_in[0];   // z_e, 65536 x 256 fp32
    const float* cb = (const float*)d_in[1];   // codebook, 1024 x 256 fp32
    float* out = (float*)d_out;                // z_q (16777216) ++ loss (1)

    float* half_esq = (float*)d_ws;                         // 4 KB
    short* cb_frag  = (short*)((char*)d_ws + 4096);         // 512 KB bf16 fragments

    vq_esq_kernel<<<16, 256, 0, stream>>>(cb, half_esq, out + ND);
    vq_convert_kernel<<<128, 256, 0, stream>>>(cb, cb_frag);
    vq_gemm_kernel<<<NTOT / 64, 256, 0, stream>>>(z, cb, cb_frag, half_esq, out);
}